// Round 4
// baseline (74.751 us; speedup 1.0000x reference)
//
#include <hip/hip_runtime.h>
#include <math.h>

// MeanAggregator: time-decayed neighbor mean.
// Shapes: nodes[B], neigh_ids[B,K=32], neigh_times[B,K], features[N,D=128] fp32.
// out[B,D] = (F[nodes] + sum_j w_j F[neigh_j]) / denom, with
//   w_j = (t_j <= 100) ? exp((t_j-100)/100) : 0,  S = sum w_j, T = (S==0?1:S),
//   denom = 1 + S/T.
//
// Memory-bound gather at ~487 MB/launch. Feature table (244 MiB) nearly fits
// the 256 MiB Infinity Cache; streamed-once data (ids, times, out) is marked
// non-temporal so L3 capacity is reserved for feature rows across replays.
//
// One 64-lane wave per output row, two 32-lane halves; half h processes
// neighbors k = 2i+h; lane (h,c) owns dims 4c..4c+3 (float4) -> each gathered
// row is one coalesced 512B half-wave dwordx4 transaction. Invalid neighbors
// (w_k == 0, ~50%) are skipped at half-wave exec-mask granularity.

// Native clang vector type — required by __builtin_nontemporal_{load,store}
// (HIP's float4 is a class and is rejected).
typedef float vfloat4 __attribute__((ext_vector_type(4)));

__global__ __launch_bounds__(256) void mean_agg_kernel(
    const int*   __restrict__ nodes,        // [B]
    const int*   __restrict__ neigh_ids,    // [B,32]
    const float* __restrict__ neigh_times,  // [B,32]
    const float* __restrict__ features,     // [N,128]
    float*       __restrict__ out,          // [B,128]
    int B)
{
    const int wave = threadIdx.x >> 6;            // 4 waves / block
    const int lane = threadIdx.x & 63;
    const int half = lane >> 5;                   // 0 or 1
    const int c    = lane & 31;                   // dim chunk: dims 4c..4c+3
    const int row  = blockIdx.x * 4 + wave;
    if (row >= B) return;                          // wave-uniform exit

    // Lanes l and l+32 mirror neighbor j = c. Streamed-once: non-temporal.
    const float t  = __builtin_nontemporal_load(&neigh_times[row * 32 + c]);
    const int  idj = __builtin_nontemporal_load(&neigh_ids[row * 32 + c]);
    float wj = (t <= 100.0f) ? __expf((t - 100.0f) * 0.01f) : 0.0f;

    // S = sum of w over the 32 neighbors (butterfly within each 32-half)
    float S = wj;
    #pragma unroll
    for (int m = 1; m < 32; m <<= 1)
        S += __shfl_xor(S, m);

    const float T     = (S == 0.0f) ? 1.0f : S;
    const float denom = 1.0f + S / T;

    // Weighted gather-accumulate: half h takes neighbors 2i+h.
    vfloat4 acc = (vfloat4)(0.0f);
    #pragma unroll
    for (int i = 0; i < 16; ++i) {
        const int   k   = 2 * i + half;
        const float wk  = __shfl(wj, k);           // half-wave-uniform
        const int   idk = __shfl(idj, k);          // hoisted out of the branch
        if (wk != 0.0f) {
            const vfloat4 f = *reinterpret_cast<const vfloat4*>(
                &features[(size_t)idk * 128 + c * 4]);
            acc += wk * f;
        }
    }
    // Combine the two halves (disjoint neighbor subsets, same dims).
    acc.x += __shfl_xor(acc.x, 32);
    acc.y += __shfl_xor(acc.y, 32);
    acc.z += __shfl_xor(acc.z, 32);
    acc.w += __shfl_xor(acc.w, 32);

    // Self row: cacheable (part of the feature table).
    const int self = __builtin_nontemporal_load(&nodes[row]);
    const vfloat4 fs = *reinterpret_cast<const vfloat4*>(
        &features[(size_t)self * 128 + c * 4]);

    const float inv_d  = 1.0f / denom;
    const float inv_td = 1.0f / (T * denom);
    const vfloat4 o = fs * inv_d + acc * inv_td;

    // One coalesced 512B non-temporal store from the lower half-wave.
    if (half == 0)
        __builtin_nontemporal_store(o,
            reinterpret_cast<vfloat4*>(&out[(size_t)row * 128 + c * 4]));
}

extern "C" void kernel_launch(void* const* d_in, const int* in_sizes, int n_in,
                              void* d_out, int out_size, void* d_ws, size_t ws_size,
                              hipStream_t stream) {
    const int*   nodes       = (const int*)  d_in[0];
    const int*   neigh_ids   = (const int*)  d_in[1];
    const float* neigh_times = (const float*)d_in[2];
    const float* features    = (const float*)d_in[3];
    float*       out         = (float*)      d_out;

    const int B = in_sizes[0];                 // 50000
    const int rows_per_block = 4;              // 4 waves/block
    const int grid = (B + rows_per_block - 1) / rows_per_block;

    mean_agg_kernel<<<grid, 256, 0, stream>>>(nodes, neigh_ids, neigh_times,
                                              features, out, B);
}

// Round 5
// 71.515 us; speedup vs baseline: 1.0453x; 1.0453x over previous
//
#include <hip/hip_runtime.h>
#include <math.h>

// MeanAggregator: time-decayed neighbor mean.
// Shapes: nodes[B], neigh_ids[B,K=32], neigh_times[B,K], features[N,D=128] fp32.
// out[B,D] = (F[nodes] + sum_j w_j F[neigh_j]) / denom, with
//   w_j = (t_j <= 100) ? exp((t_j-100)/100) : 0,  S = sum w_j, T = (S==0?1:S),
//   denom = 1 + S/T.
//
// Memory-bound gather, ~474 MB/launch irreducible. nt-hints were neutral
// (Round 3) -> reverted. This round: quarter-wave decomposition to maximize
// rows in flight per instruction.
//
// One 64-lane wave per output row, four 16-lane quarters; quarter q processes
// neighbors k = 4i+q; lane (q,c) owns dims 8c..8c+7 (two float4 loads,
// 32 B/lane) -> each load-instruction pair covers FOUR feature rows (4 x 512B
// contiguous segments). Invalid neighbors (w_k == 0, ~50%) skipped at
// quarter-wave exec-mask granularity. Two-level shfl_xor(16,32) combines the
// quarters' partial sums.

typedef float vfloat4 __attribute__((ext_vector_type(4)));

__global__ __launch_bounds__(256) void mean_agg_kernel(
    const int*   __restrict__ nodes,        // [B]
    const int*   __restrict__ neigh_ids,    // [B,32]
    const float* __restrict__ neigh_times,  // [B,32]
    const float* __restrict__ features,     // [N,128]
    float*       __restrict__ out,          // [B,128]
    int B)
{
    const int wave = threadIdx.x >> 6;            // 4 waves / block
    const int lane = threadIdx.x & 63;
    const int q    = lane >> 4;                   // quarter 0..3
    const int c    = lane & 15;                   // dim chunk: dims 8c..8c+7
    const int row  = blockIdx.x * 4 + wave;
    if (row >= B) return;                          // wave-uniform exit

    // Lanes l and l+32 mirror neighbor j = lane&31 (for the weight reduce).
    const int j = lane & 31;
    const float t  = neigh_times[row * 32 + j];
    const int  idj = neigh_ids[row * 32 + j];
    float wj = (t <= 100.0f) ? __expf((t - 100.0f) * 0.01f) : 0.0f;

    // S = sum of w over the 32 neighbors (butterfly within each 32-half).
    float S = wj;
    #pragma unroll
    for (int m = 1; m < 32; m <<= 1)
        S += __shfl_xor(S, m);

    const float T     = (S == 0.0f) ? 1.0f : S;
    const float denom = 1.0f + S / T;

    // Weighted gather-accumulate: quarter q takes neighbors k = 4i+q.
    vfloat4 acc0 = (vfloat4)(0.0f);
    vfloat4 acc1 = (vfloat4)(0.0f);
    #pragma unroll
    for (int i = 0; i < 8; ++i) {
        const int   k   = 4 * i + q;
        const float wk  = __shfl(wj, k);           // quarter-uniform
        const int   idk = __shfl(idj, k);
        if (wk != 0.0f) {
            const float* fp = &features[(size_t)idk * 128 + c * 8];
            const vfloat4 f0 = *reinterpret_cast<const vfloat4*>(fp);
            const vfloat4 f1 = *reinterpret_cast<const vfloat4*>(fp + 4);
            acc0 += wk * f0;
            acc1 += wk * f1;
        }
    }
    // Combine the four quarters (disjoint neighbor subsets, same dims).
    #pragma unroll
    for (int m = 16; m <= 32; m <<= 1) {
        acc0.x += __shfl_xor(acc0.x, m);
        acc0.y += __shfl_xor(acc0.y, m);
        acc0.z += __shfl_xor(acc0.z, m);
        acc0.w += __shfl_xor(acc0.w, m);
        acc1.x += __shfl_xor(acc1.x, m);
        acc1.y += __shfl_xor(acc1.y, m);
        acc1.z += __shfl_xor(acc1.z, m);
        acc1.w += __shfl_xor(acc1.w, m);
    }

    // Self row + output: quarter 0 only (16 lanes x 32 B = one 512 B row).
    if (q == 0) {
        const int self = nodes[row];
        const float* sp = &features[(size_t)self * 128 + c * 8];
        const vfloat4 fs0 = *reinterpret_cast<const vfloat4*>(sp);
        const vfloat4 fs1 = *reinterpret_cast<const vfloat4*>(sp + 4);

        const float inv_d  = 1.0f / denom;
        const float inv_td = 1.0f / (T * denom);
        const vfloat4 o0 = fs0 * inv_d + acc0 * inv_td;
        const vfloat4 o1 = fs1 * inv_d + acc1 * inv_td;

        float* op = &out[(size_t)row * 128 + c * 8];
        *reinterpret_cast<vfloat4*>(op)     = o0;
        *reinterpret_cast<vfloat4*>(op + 4) = o1;
    }
}

extern "C" void kernel_launch(void* const* d_in, const int* in_sizes, int n_in,
                              void* d_out, int out_size, void* d_ws, size_t ws_size,
                              hipStream_t stream) {
    const int*   nodes       = (const int*)  d_in[0];
    const int*   neigh_ids   = (const int*)  d_in[1];
    const float* neigh_times = (const float*)d_in[2];
    const float* features    = (const float*)d_in[3];
    float*       out         = (float*)      d_out;

    const int B = in_sizes[0];                 // 50000
    const int rows_per_block = 4;              // 4 waves/block
    const int grid = (B + rows_per_block - 1) / rows_per_block;

    mean_agg_kernel<<<grid, 256, 0, stream>>>(nodes, neigh_ids, neigh_times,
                                              features, out, B);
}